// Round 7
// baseline (409.721 us; speedup 1.0000x reference)
//
#include <hip/hip_runtime.h>

#define HSZ 64
#define ISZ 8
#define TSZ 512

typedef _Float16 f16;
typedef __attribute__((ext_vector_type(8))) _Float16 f16x8;
typedef __attribute__((ext_vector_type(4))) float f32x4;
typedef unsigned short u16;

__device__ __forceinline__ u16 f16bits(float f) {
    union { f16 h; u16 u; } v; v.h = (f16)f;
    return v.u;
}

// One wave per 4 batch rows (grid 1024 = 1 wave/SIMD). Everything wave-local:
// no __syncthreads, no cross-wave LDS. Batch rows sit at MFMA tile rows
// {0,4,8,12} so every valid gate pre-act lands in acc reg 0 (C row = 4*lg) --
// activation runs on all 64 lanes with NO cross-lane redistribution.
// K layout: kt0 = h[0,32), kt1 = h[32,64), kt2 = x[0,8) | 1,1 (bias hi/lo) | 0.
// Per step: 3 ds_read_b128 + 48 MFMA + act(4 units/lane) + 4 ds_write_b16.
__global__ __launch_bounds__(64, 1) void lstm_reg(
    const float* __restrict__ x,      // [B, T, I]
    const float* __restrict__ W_ih,   // [4H, I]
    const float* __restrict__ W_hh,   // [4H, H]
    const float* __restrict__ b_ih,   // [4H]
    const float* __restrict__ b_hh,   // [4H]
    const float* __restrict__ W_fc,   // [O, H]
    const float* __restrict__ b_fc,   // [O]
    float* __restrict__ out)          // [B, O]
{
    const int l  = threadIdx.x;       // 0..63
    const int s  = l & 15;            // tile col (act) / tile row (A-supply)
    const int lg = l >> 4;            // k-group / batch row (act)
    const int B0 = blockIdx.x * 4;

    // wave-private LDS; row strides chosen so all accesses are <=2-way (free)
    __shared__ __align__(16) u16 hbuf[4][80];      // h, rows=batch, cols [0,64); 64..79 pad
    __shared__ __align__(16) u16 xbuf[2][4][32];   // x | 1,1 | zeros

    // zero LDS (single wave -- ordering via in-order DS pipe, no barrier)
    {
        unsigned* p = (unsigned*)&hbuf[0][0];
#pragma unroll
        for (int i = 0; i < 3; ++i) { int k = l + 64 * i; if (k < 160) p[k] = 0; }
        unsigned* q = (unsigned*)&xbuf[0][0][0];
        q[l] = 0; q[l + 64] = 0;
    }
    // constant 1.0 at cols 8,9 (bias rows of the kt2 MFMA), both x buffers
    if (l < 16) {
        const int bf = l >> 3, idx = l & 7, r = idx >> 1, c = 8 + (idx & 1);
        xbuf[bf][r][c] = 0x3C00;  // 1.0 in f16
    }

    // ---- weights into registers ----
    // B-frag (16x16x32): lane holds col gc = 16n+s, k = 32kt + lg*8 + j.
    f16x8 bh[16][2];   // W_hh
    f16x8 bxf[16];     // kt2: x-weights (lg=0), bias hi/lo at k=72,73 (lg=1)
#pragma unroll
    for (int n = 0; n < 16; ++n) {
        const int gc = n * 16 + s;   // gate row in [0,256)
#pragma unroll
        for (int kt = 0; kt < 2; ++kt) {
            const float4 a = *reinterpret_cast<const float4*>(&W_hh[gc * HSZ + kt * 32 + lg * 8]);
            const float4 b = *reinterpret_cast<const float4*>(&W_hh[gc * HSZ + kt * 32 + lg * 8 + 4]);
            bh[n][kt][0] = (f16)a.x; bh[n][kt][1] = (f16)a.y;
            bh[n][kt][2] = (f16)a.z; bh[n][kt][3] = (f16)a.w;
            bh[n][kt][4] = (f16)b.x; bh[n][kt][5] = (f16)b.y;
            bh[n][kt][6] = (f16)b.z; bh[n][kt][7] = (f16)b.w;
        }
        f16x8 v;
#pragma unroll
        for (int j = 0; j < 8; ++j) v[j] = (f16)0.0f;
        if (lg == 0) {               // k = 64..71 -> W_ih row gc
            const float4 a = *reinterpret_cast<const float4*>(&W_ih[gc * ISZ]);
            const float4 b = *reinterpret_cast<const float4*>(&W_ih[gc * ISZ + 4]);
            v[0] = (f16)a.x; v[1] = (f16)a.y; v[2] = (f16)a.z; v[3] = (f16)a.w;
            v[4] = (f16)b.x; v[5] = (f16)b.y; v[6] = (f16)b.z; v[7] = (f16)b.w;
        } else if (lg == 1) {        // k = 72,73 -> bias hi/lo split
            const float bs = b_ih[gc] + b_hh[gc];
            const f16 hi = (f16)bs;
            v[0] = hi;
            v[1] = (f16)(bs - (float)hi);
        }
        bxf[n] = v;
    }

    // stage x(0)
    const float* xptr = x + (size_t)(B0 + (l >> 3)) * TSZ * ISZ + (l & 7);
    if (l < 32)
        xbuf[0][l >> 3][l & 7] = f16bits(xptr[0]);

    float c4[4] = {0.f, 0.f, 0.f, 0.f};
    float h4[4] = {0.f, 0.f, 0.f, 0.f};
    const f32x4 zero4 = {0.f, 0.f, 0.f, 0.f};
    const int arow = s >> 2;          // batch row this lane's A-frag supplies
    const float L1 = 1.442695041f;    // log2(e)
    const float L2 = 2.885390082f;    // 2*log2(e)

    for (int t = 0; t < TSZ; ++t) {
        const int bf = t & 1;

        // prefetch x(t+1) early (hides HBM latency under MFMA+act)
        float xv = 0.f;
        if (l < 32 && t + 1 < TSZ)
            xv = xptr[(size_t)(t + 1) * ISZ];

        // A-frags: row (l&15) supplies batch arow; rows not in {0,4,8,12}
        // duplicate a valid row -- their C rows are never read.
        const f16x8 a0 = *reinterpret_cast<const f16x8*>(&hbuf[arow][lg * 8]);
        const f16x8 a1 = *reinterpret_cast<const f16x8*>(&hbuf[arow][32 + lg * 8]);
        const f16x8 a2 = *reinterpret_cast<const f16x8*>(&xbuf[bf][arow][lg * 8]);

        f32x4 acc[16];
#pragma unroll
        for (int n = 0; n < 16; ++n) {
            acc[n] = __builtin_amdgcn_mfma_f32_16x16x32_f16(a2, bxf[n],   zero4,  0, 0, 0);
            acc[n] = __builtin_amdgcn_mfma_f32_16x16x32_f16(a0, bh[n][0], acc[n], 0, 0, 0);
            acc[n] = __builtin_amdgcn_mfma_f32_16x16x32_f16(a1, bh[n][1], acc[n], 0, 0, 0);
        }

        // act: lane owns batch row lg, hidden units 16u + s (u=0..3), all in reg 0.
        // gate g of unit u is acc[4g+u][0]. Common-denominator form: 5 exp2 + 2 rcp.
#pragma unroll
        for (int u = 0; u < 4; ++u) {
            const float pi = acc[u][0];
            const float pf = acc[4 + u][0];
            const float pg = acc[8 + u][0];
            const float po = acc[12 + u][0];
            const float ea = __builtin_amdgcn_exp2f(-L1 * pi);
            const float eb = __builtin_amdgcn_exp2f(-L1 * pf);
            const float ed = __builtin_amdgcn_exp2f(-L2 * pg);
            const float es = __builtin_amdgcn_exp2f(-L1 * po);
            const float A1 = 1.0f + ea, Bv = 1.0f + eb, D1 = 1.0f + ed;
            const float R1 = __builtin_amdgcn_rcpf(A1 * Bv * D1);
            c4[u] = fmaf(c4[u] * A1, D1, (1.0f - ed) * Bv) * R1;
            const float eu = __builtin_amdgcn_exp2f(-L2 * c4[u]);
            const float R2 = __builtin_amdgcn_rcpf((1.0f + es) * (1.0f + eu));
            h4[u] = (1.0f - eu) * R2;
            hbuf[lg][u * 16 + s] = f16bits(h4[u]);   // conflict-free per write
        }

        // stage prefetched x(t+1) into the other buffer
        if (l < 32 && t + 1 < TSZ)
            xbuf[bf ^ 1][l >> 3][l & 7] = f16bits(xv);
    }

    // ---- final FC: out[b] = sum_c h(b,c) * W_fc[c] + b_fc ----
    float v = 0.f;
#pragma unroll
    for (int u = 0; u < 4; ++u)
        v = fmaf(h4[u], W_fc[u * 16 + s], v);
    v += __shfl_xor(v, 1);
    v += __shfl_xor(v, 2);
    v += __shfl_xor(v, 4);
    v += __shfl_xor(v, 8);
    if (s == 0)
        out[B0 + lg] = v + b_fc[0];
}

extern "C" void kernel_launch(void* const* d_in, const int* in_sizes, int n_in,
                              void* d_out, int out_size, void* d_ws, size_t ws_size,
                              hipStream_t stream) {
    const float* x    = (const float*)d_in[0];
    const float* W_ih = (const float*)d_in[1];
    const float* W_hh = (const float*)d_in[2];
    const float* b_ih = (const float*)d_in[3];
    const float* b_hh = (const float*)d_in[4];
    const float* W_fc = (const float*)d_in[5];
    const float* b_fc = (const float*)d_in[6];
    float* out = (float*)d_out;

    const int B = in_sizes[0] / (TSZ * ISZ);  // 4096
    lstm_reg<<<B / 4, 64, 0, stream>>>(x, W_ih, W_hh, b_ih, b_hh, W_fc, b_fc, out);
}

// Round 8
// 268.525 us; speedup vs baseline: 1.5258x; 1.5258x over previous
//
#include <hip/hip_runtime.h>

#define HSZ 64
#define ISZ 8
#define TSZ 512
#define BTILE 16   // batch rows per block
#define NW 16      // waves per block (1024 threads) -> 4 waves/SIMD
#define KP 104     // k per row: [0,64) h | [64,72) x | 72,73 bias-activator | zero; 208B stride

typedef _Float16 f16;
typedef __attribute__((ext_vector_type(8))) _Float16 f16x8;
typedef __attribute__((ext_vector_type(4))) float f32x4;
typedef unsigned short u16;

__device__ __forceinline__ u16 f16bits(float f) {
    union { f16 h; u16 u; } v; v.h = (f16)f;
    return v.u;
}

// Operand-swapped MFMA LSTM. A = weights (M = 16 gate rows), B = h/x (N = 16 batch).
// Wave w's M-rows: gc(m) = (m&3)*64 + 4w + (m>>2)  (4 gates x 4 hidden units).
// C layout (col=lane&15=batch, row=4*lg+reg) => lane (lr,lg) holds ALL 4 gates of
// unit (batch=lr, hidden=4w+lg) in acc[0..3]: act is fully lane-local, no shuffles.
// Weights pre-scaled by -log2(e) (gates i,f,o) / -2log2(e) (gate g) so act uses
// exp2 directly. Bias enters via B=1.0 at k=72,73 against f16 hi/lo bias in A.
// H double-buffered: reads from H[buf], all writes to H[buf^1]; ONE barrier/step.
__global__ __launch_bounds__(1024, 4) void lstm_w16(
    const float* __restrict__ x,      // [B, T, I]
    const float* __restrict__ W_ih,   // [4H, I]
    const float* __restrict__ W_hh,   // [4H, H]
    const float* __restrict__ b_ih,   // [4H]
    const float* __restrict__ b_hh,   // [4H]
    const float* __restrict__ W_fc,   // [O, H]
    const float* __restrict__ b_fc,   // [O]
    float* __restrict__ out)          // [B, O]
{
    const int tid = threadIdx.x;
    const int w  = tid >> 6;          // wave 0..15, owns hidden units [4w, 4w+4)
    const int l  = tid & 63;
    const int lr = l & 15;            // A: M-row sel / B,C: batch col
    const int lg = l >> 4;            // k-group; act: hidden unit 4w+lg
    const int B0 = blockIdx.x * BTILE;

    __shared__ __align__(16) u16 H[2][BTILE][KP];  // [buf][batch row][k]
    __shared__ float red[NW][BTILE];

    for (int i = tid; i < 2 * BTILE * KP; i += 1024)
        ((u16*)H)[i] = 0;
    __syncthreads();
    // bias-activator 1.0 at k=72,73 (both buffers), and x(0) into buf 0
    if (tid < 64) {
        const int b = tid >> 5, r = (tid >> 1) & 15, k = 72 + (tid & 1);
        H[b][r][k] = 0x3C00;   // f16 1.0
    }
    if (l < 8)
        H[0][w][HSZ + l] = f16bits(x[((size_t)(B0 + w) * TSZ + 0) * ISZ + l]);

    // ---- A-fragments (weights, M-side) into registers, pre-scaled ----
    const int gate = lr & 3;
    const int gc   = gate * HSZ + 4 * w + (lr >> 2);   // gate row in [0,256)
    const float sc = (gate == 2) ? -2.885390082f : -1.442695041f;
    f16x8 wa0, wa1, wa2;
    {
        const float4 a = *reinterpret_cast<const float4*>(&W_hh[gc * HSZ + lg * 8]);
        const float4 b = *reinterpret_cast<const float4*>(&W_hh[gc * HSZ + lg * 8 + 4]);
        wa0[0] = (f16)(sc * a.x); wa0[1] = (f16)(sc * a.y);
        wa0[2] = (f16)(sc * a.z); wa0[3] = (f16)(sc * a.w);
        wa0[4] = (f16)(sc * b.x); wa0[5] = (f16)(sc * b.y);
        wa0[6] = (f16)(sc * b.z); wa0[7] = (f16)(sc * b.w);
    }
    {
        const float4 a = *reinterpret_cast<const float4*>(&W_hh[gc * HSZ + 32 + lg * 8]);
        const float4 b = *reinterpret_cast<const float4*>(&W_hh[gc * HSZ + 32 + lg * 8 + 4]);
        wa1[0] = (f16)(sc * a.x); wa1[1] = (f16)(sc * a.y);
        wa1[2] = (f16)(sc * a.z); wa1[3] = (f16)(sc * a.w);
        wa1[4] = (f16)(sc * b.x); wa1[5] = (f16)(sc * b.y);
        wa1[6] = (f16)(sc * b.z); wa1[7] = (f16)(sc * b.w);
    }
#pragma unroll
    for (int j = 0; j < 8; ++j) wa2[j] = (f16)0.0f;
    if (lg == 0) {                    // k 64..71 -> x weights
        const float4 a = *reinterpret_cast<const float4*>(&W_ih[gc * ISZ]);
        const float4 b = *reinterpret_cast<const float4*>(&W_ih[gc * ISZ + 4]);
        wa2[0] = (f16)(sc * a.x); wa2[1] = (f16)(sc * a.y);
        wa2[2] = (f16)(sc * a.z); wa2[3] = (f16)(sc * a.w);
        wa2[4] = (f16)(sc * b.x); wa2[5] = (f16)(sc * b.y);
        wa2[6] = (f16)(sc * b.z); wa2[7] = (f16)(sc * b.w);
    } else if (lg == 1) {             // k 72,73 -> bias hi/lo (pre-scaled)
        const float bs = sc * (b_ih[gc] + b_hh[gc]);
        const f16 hi = (f16)bs;
        wa2[0] = hi;
        wa2[1] = (f16)(bs - (float)hi);
    }
    __syncthreads();

    float c = 0.0f, h = 0.0f;
    const int hcol = 4 * w + lg;      // this lane's hidden unit
    const float L2 = 2.885390082f;

    for (int t = 0; t < TSZ; ++t) {
        const int buf = t & 1, nb = buf ^ 1;

        // prefetch x(t+1): wave w covers batch row w, lanes 0..7
        float xv = 0.0f;
        if (l < 8 && t + 1 < TSZ)
            xv = x[((size_t)(B0 + w) * TSZ + (t + 1)) * ISZ + l];

        // B-fragments (h/x, N = batch): lane reads batch row lr, k = base + lg*8
        const u16* rp = &H[buf][lr][0];
        const f16x8 b0 = *reinterpret_cast<const f16x8*>(rp + lg * 8);
        const f16x8 b1 = *reinterpret_cast<const f16x8*>(rp + 32 + lg * 8);
        const f16x8 b2 = *reinterpret_cast<const f16x8*>(rp + 64 + lg * 8);

        f32x4 acc = {0.f, 0.f, 0.f, 0.f};
        acc = __builtin_amdgcn_mfma_f32_16x16x32_f16(wa2, b2, acc, 0, 0, 0);
        acc = __builtin_amdgcn_mfma_f32_16x16x32_f16(wa0, b0, acc, 0, 0, 0);
        acc = __builtin_amdgcn_mfma_f32_16x16x32_f16(wa1, b1, acc, 0, 0, 0);

        // act: acc[r] = pre-scaled gate r (i,f,g,o) of (batch lr, hidden hcol).
        // common-denominator form: 5 exp2 + 2 rcp, all f32.
        const float ea = __builtin_amdgcn_exp2f(acc[0]);
        const float eb = __builtin_amdgcn_exp2f(acc[1]);
        const float ed = __builtin_amdgcn_exp2f(acc[2]);
        const float es = __builtin_amdgcn_exp2f(acc[3]);
        const float A1 = 1.0f + ea, B1 = 1.0f + eb, D1 = 1.0f + ed;
        const float R1 = __builtin_amdgcn_rcpf(A1 * B1 * D1);
        c = fmaf(c * A1, D1, (1.0f - ed) * B1) * R1;
        const float eu = __builtin_amdgcn_exp2f(-L2 * c);
        const float R2 = __builtin_amdgcn_rcpf((1.0f + es) * (1.0f + eu));
        h = (1.0f - eu) * R2;

        H[nb][lr][hcol] = f16bits(h);
        if (l < 8 && t + 1 < TSZ)
            H[nb][w][HSZ + l] = f16bits(xv);
        __syncthreads();
    }

    // ---- final FC: out[b] = sum_h h(b,hu) * W_fc[hu] + b_fc ----
    float v = h * W_fc[hcol];
    v += __shfl_xor(v, 16);
    v += __shfl_xor(v, 32);           // sum over lg: wave-partial per batch row lr
    if (lg == 0) red[w][lr] = v;
    __syncthreads();
    if (tid < BTILE) {
        float s = b_fc[0];
#pragma unroll
        for (int ww = 0; ww < NW; ++ww) s += red[ww][tid];
        out[B0 + tid] = s;
    }
}

extern "C" void kernel_launch(void* const* d_in, const int* in_sizes, int n_in,
                              void* d_out, int out_size, void* d_ws, size_t ws_size,
                              hipStream_t stream) {
    const float* x    = (const float*)d_in[0];
    const float* W_ih = (const float*)d_in[1];
    const float* W_hh = (const float*)d_in[2];
    const float* b_ih = (const float*)d_in[3];
    const float* b_hh = (const float*)d_in[4];
    const float* W_fc = (const float*)d_in[5];
    const float* b_fc = (const float*)d_in[6];
    float* out = (float*)d_out;

    const int B = in_sizes[0] / (TSZ * ISZ);  // 4096
    lstm_w16<<<B / BTILE, NW * 64, 0, stream>>>(x, W_ih, W_hh, b_ih, b_hh, W_fc, b_fc, out);
}

// Round 9
// 253.721 us; speedup vs baseline: 1.6149x; 1.0583x over previous
//
#include <hip/hip_runtime.h>

#define HSZ 64
#define ISZ 8
#define TSZ 512
#define BTILE 16   // batch rows per block
#define NW 16      // waves per block (1024 threads) -> 4 waves/SIMD
#define KP 104     // k per row: [0,64) h | [64,72) x | [72,96) zero (read-only pad) | pad

typedef _Float16 f16;
typedef __attribute__((ext_vector_type(8))) _Float16 f16x8;
typedef __attribute__((ext_vector_type(4))) float f32x4;
typedef unsigned short u16;

__device__ __forceinline__ u16 f16bits(float f) {
    union { f16 h; u16 u; } v; v.h = (f16)f;
    return v.u;
}

// Operand-swapped MFMA LSTM (r8 structure) + overhead strip:
//  - bias enters as the MFMA C-in (exact f32, pre-scaled by -log2e / -2log2e)
//  - 2x unrolled timestep loop: static double-buffer pointers, hoisted offsets
// A = weights (M = 16 gate rows: gc(m)=(m&3)*64+4w+(m>>2)), B = h/x (N = 16 batch).
// C layout: lane (lr,lg) holds all 4 gates of unit (batch lr, hidden 4w+lg) in
// acc[0..3] -> act fully lane-local. One barrier per step.
__global__ __launch_bounds__(1024, 4) void lstm_w16b(
    const float* __restrict__ x,      // [B, T, I]
    const float* __restrict__ W_ih,   // [4H, I]
    const float* __restrict__ W_hh,   // [4H, H]
    const float* __restrict__ b_ih,   // [4H]
    const float* __restrict__ b_hh,   // [4H]
    const float* __restrict__ W_fc,   // [O, H]
    const float* __restrict__ b_fc,   // [O]
    float* __restrict__ out)          // [B, O]
{
    const int tid = threadIdx.x;
    const int w  = tid >> 6;          // wave 0..15, owns hidden units [4w, 4w+4)
    const int l  = tid & 63;
    const int lr = l & 15;            // A: M-row sel / B,C: batch col
    const int lg = l >> 4;            // k-group; act: hidden unit 4w+lg
    const int B0 = blockIdx.x * BTILE;
    const int hcol = 4 * w + lg;      // this lane's hidden unit

    __shared__ __align__(16) u16 H[2][BTILE][KP];  // [buf][batch row][k]
    __shared__ float red[NW][BTILE];

    for (int i = tid; i < 2 * BTILE * KP; i += 1024)
        ((u16*)H)[i] = 0;

    // ---- A-fragments (weights, M-side) into registers, pre-scaled ----
    const int gate = lr & 3;
    const int gc   = gate * HSZ + 4 * w + (lr >> 2);   // gate row in [0,256)
    const float sc = (gate == 2) ? -2.885390082f : -1.442695041f;
    f16x8 wa0, wa1, wa2;
    {
        const float4 a = *reinterpret_cast<const float4*>(&W_hh[gc * HSZ + lg * 8]);
        const float4 b = *reinterpret_cast<const float4*>(&W_hh[gc * HSZ + lg * 8 + 4]);
        wa0[0] = (f16)(sc * a.x); wa0[1] = (f16)(sc * a.y);
        wa0[2] = (f16)(sc * a.z); wa0[3] = (f16)(sc * a.w);
        wa0[4] = (f16)(sc * b.x); wa0[5] = (f16)(sc * b.y);
        wa0[6] = (f16)(sc * b.z); wa0[7] = (f16)(sc * b.w);
    }
    {
        const float4 a = *reinterpret_cast<const float4*>(&W_hh[gc * HSZ + 32 + lg * 8]);
        const float4 b = *reinterpret_cast<const float4*>(&W_hh[gc * HSZ + 32 + lg * 8 + 4]);
        wa1[0] = (f16)(sc * a.x); wa1[1] = (f16)(sc * a.y);
        wa1[2] = (f16)(sc * a.z); wa1[3] = (f16)(sc * a.w);
        wa1[4] = (f16)(sc * b.x); wa1[5] = (f16)(sc * b.y);
        wa1[6] = (f16)(sc * b.z); wa1[7] = (f16)(sc * b.w);
    }
#pragma unroll
    for (int j = 0; j < 8; ++j) wa2[j] = (f16)0.0f;
    if (lg == 0) {                    // k 64..71 -> x weights (zeros for lg>=1:
        const float4 a = *reinterpret_cast<const float4*>(&W_ih[gc * ISZ]);      // their
        const float4 b = *reinterpret_cast<const float4*>(&W_ih[gc * ISZ + 4]);  // B-reads
        wa2[0] = (f16)(sc * a.x); wa2[1] = (f16)(sc * a.y);                      // are
        wa2[2] = (f16)(sc * a.z); wa2[3] = (f16)(sc * a.w);                      // don't-care)
        wa2[4] = (f16)(sc * b.x); wa2[5] = (f16)(sc * b.y);
        wa2[6] = (f16)(sc * b.z); wa2[7] = (f16)(sc * b.w);
    }

    // per-lane bias vector (C-in of the first MFMA): gate r of unit hcol
    f32x4 bias4;
#pragma unroll
    for (int r = 0; r < 4; ++r) {
        const float s = (r == 2) ? -2.885390082f : -1.442695041f;
        bias4[r] = s * (b_ih[r * HSZ + hcol] + b_hh[r * HSZ + hcol]);
    }

    __syncthreads();  // zeroing visible

    // stage x(0) into buf 0: wave w covers batch row w, lanes 0..7
    const float* xptr = x + (size_t)(B0 + w) * TSZ * ISZ + l;   // valid for l<8
    if (l < 8)
        H[0][w][HSZ + l] = f16bits(xptr[0]);
    __syncthreads();

    // hoisted LDS offsets (u16 units)
    const u16* rd0 = &H[0][lr][lg * 8];
    const u16* rd1 = &H[1][lr][lg * 8];
    u16* wr0 = &H[0][lr][hcol];
    u16* wr1 = &H[1][lr][hcol];
    u16* xs0 = &H[0][w][HSZ + l];     // used by l<8 only
    u16* xs1 = &H[1][w][HSZ + l];

    float c = 0.0f, h = 0.0f;
    const float L2 = 2.885390082f;

#define STEP(RD, WR, XS, XIDX, XGUARD)                                           \
    {                                                                            \
        float xv = 0.0f;                                                         \
        if ((l < 8) && (XGUARD))                                                 \
            xv = xptr[(size_t)(XIDX) * ISZ];                                     \
        const f16x8 b0 = *reinterpret_cast<const f16x8*>(RD);                    \
        const f16x8 b1 = *reinterpret_cast<const f16x8*>(RD + 32);               \
        const f16x8 b2 = *reinterpret_cast<const f16x8*>(RD + 64);               \
        f32x4 acc = __builtin_amdgcn_mfma_f32_16x16x32_f16(wa2, b2, bias4, 0, 0, 0); \
        acc = __builtin_amdgcn_mfma_f32_16x16x32_f16(wa0, b0, acc, 0, 0, 0);     \
        acc = __builtin_amdgcn_mfma_f32_16x16x32_f16(wa1, b1, acc, 0, 0, 0);     \
        const float ea = __builtin_amdgcn_exp2f(acc[0]);                         \
        const float eb = __builtin_amdgcn_exp2f(acc[1]);                         \
        const float ed = __builtin_amdgcn_exp2f(acc[2]);                         \
        const float es = __builtin_amdgcn_exp2f(acc[3]);                         \
        const float A1 = 1.0f + ea, B1 = 1.0f + eb, D1 = 1.0f + ed;              \
        const float R1 = __builtin_amdgcn_rcpf(A1 * B1 * D1);                    \
        c = fmaf(c * A1, D1, (1.0f - ed) * B1) * R1;                             \
        const float eu = __builtin_amdgcn_exp2f(-L2 * c);                        \
        const float R2 = __builtin_amdgcn_rcpf((1.0f + es) * (1.0f + eu));       \
        h = (1.0f - eu) * R2;                                                    \
        *(WR) = f16bits(h);                                                      \
        if ((l < 8) && (XGUARD))                                                 \
            *(XS) = f16bits(xv);                                                 \
        __syncthreads();                                                         \
    }

    for (int t = 0; t < TSZ; t += 2) {
        // step t: read buf0, write h/x into buf1. x(t+1) always exists (t+1 odd <= 511).
        STEP(rd0, wr1, xs1, t + 1, true)
        // step t+1: read buf1, write into buf0. x(t+2) exists unless t == 510.
        STEP(rd1, wr0, xs0, t + 2, t < TSZ - 2)
    }
#undef STEP

    // ---- final FC: out[b] = sum_h h(b,hu) * W_fc[hu] + b_fc ----
    float v = h * W_fc[hcol];
    v += __shfl_xor(v, 16);
    v += __shfl_xor(v, 32);           // sum over lg: wave-partial per batch row lr
    if (lg == 0) red[w][lr] = v;
    __syncthreads();
    if (tid < BTILE) {
        float s = b_fc[0];
#pragma unroll
        for (int ww = 0; ww < NW; ++ww) s += red[ww][tid];
        out[B0 + tid] = s;
    }
}

extern "C" void kernel_launch(void* const* d_in, const int* in_sizes, int n_in,
                              void* d_out, int out_size, void* d_ws, size_t ws_size,
                              hipStream_t stream) {
    const float* x    = (const float*)d_in[0];
    const float* W_ih = (const float*)d_in[1];
    const float* W_hh = (const float*)d_in[2];
    const float* b_ih = (const float*)d_in[3];
    const float* b_hh = (const float*)d_in[4];
    const float* W_fc = (const float*)d_in[5];
    const float* b_fc = (const float*)d_in[6];
    float* out = (float*)d_out;

    const int B = in_sizes[0] / (TSZ * ISZ);  // 4096
    lstm_w16b<<<B / BTILE, NW * 64, 0, stream>>>(x, W_ih, W_hh, b_ih, b_hh, W_fc, b_fc, out);
}